// Round 3
// baseline (559.181 us; speedup 1.0000x reference)
//
#include <hip/hip_runtime.h>

// Unfold (im2col): IN (4,64,224,224) f32, K=3x3, pad=1, stride=1, dil=1
// (reference nh=k+dil quirk -> output spatial 223x223)
// out[ch][pos], ch=(b*64+c)*9+i*3+j (2304 channels), pos=oh*223+ow (49729)
//   = x[b,c,oh+i-1,ow+j-1] (zero-padded)
//
// V3: each output channel is a SHIFTED COPY of an input plane. Block =
// (plane q, band of R=16 output rows). Stage R+2 input rows into LDS once
// (zero-padded borders -> no validity checks in write loop), then write all
// 9 shifted copies with aligned dwordx4 stores. Global reads drop 9x and
// the store loop's VMEM mix matches the 6.2TB/s fill kernel.

#define OW       223u
#define OSP      49729u      // 223*223
#define IW       224u
#define PLANE_IN 50176u      // 224*224
#define RB       16u         // output rows per band
#define NBANDS   14u         // ceil(223/16)
#define LROWS    18u         // RB+2
#define LSTRIDE  226u        // IW+2 zero-padded cols

__global__ __launch_bounds__(256) void unfold223_v3(
    const float* __restrict__ x, float* __restrict__ out)
{
    __shared__ float lds[LROWS * LSTRIDE];   // 16,272 B

    const unsigned q    = blockIdx.y;                 // b*64+c, 0..255
    const unsigned band = blockIdx.x;                 // 0..13
    const unsigned r0   = band * RB;
    const unsigned nrow = (r0 + RB <= 223u) ? RB : (223u - r0);  // 16 or 15
    const unsigned tid  = threadIdx.x;

    const float* __restrict__ xq = x + q * PLANE_IN;

    // ---- stage input rows [r0-1, r0+nrow] into LDS, zero-padded.
    // LDS row lr <-> input row r0-1+lr ; LDS col c <-> input col c-1.
    for (unsigned lr = 0; lr < nrow + 2u; ++lr) {
        if (tid < LSTRIDE) {
            int rin = (int)r0 - 1 + (int)lr;
            int cin = (int)tid - 1;
            bool valid = ((unsigned)rin < 224u) && ((unsigned)cin < 224u);
            float v = valid ? xq[(unsigned)rin * IW + (unsigned)cin] : 0.0f;
            lds[lr * LSTRIDE + tid] = v;
        }
    }
    __syncthreads();

    // ---- emit 9 shifted copies
    const unsigned long long qbase = (unsigned long long)q * 9ull * OSP;
    for (unsigned ch9 = 0; ch9 < 9u; ++ch9) {
        const unsigned i = ch9 / 3u;          // uniform (SALU)
        const unsigned j = ch9 - i * 3u;
        // flat output segment [S, S+L) = rows [r0, r0+nrow) of this channel
        const unsigned long long S = qbase + (unsigned long long)ch9 * OSP
                                   + (unsigned long long)(r0 * OW);
        const unsigned L  = nrow * OW;
        const unsigned a  = (4u - (unsigned)(S & 3ull)) & 3u;  // align head
        const unsigned nv = (L - a) >> 2;                      // aligned quads
        const unsigned tl = L - a - 4u * nv;                   // tail elems

        // head (<=3) + tail (<=3) scalars
        if (tid < 16u) {
            unsigned pos = 0xffffffffu;
            if (tid < a) pos = tid;
            else if (tid >= 8u && tid < 8u + tl) pos = a + 4u * nv + (tid - 8u);
            if (pos != 0xffffffffu) {
                unsigned p  = r0 * OW + pos;          // pos within channel
                unsigned oh = p / OW;
                unsigned ow = p - oh * OW;
                unsigned lr = oh - r0 + i;
                out[S + pos] = lds[lr * LSTRIDE + ow + j];
            }
        }

        // main aligned quads, block-strided
        for (unsigned v = tid; v < nv; v += 256u) {
            const unsigned p   = r0 * OW + a + 4u * v;
            const unsigned oh  = p / OW;              // one magic-mul div
            const unsigned ow0 = p - oh * OW;
            const unsigned lr0 = oh - r0 + i;
            float vals[4];
#pragma unroll
            for (int e = 0; e < 4; ++e) {
                unsigned ow = ow0 + (unsigned)e;
                unsigned lr = lr0;
                if (ow >= OW) { ow -= OW; lr += 1u; }     // row-cross, chain-free
                vals[e] = lds[lr * LSTRIDE + ow + j];
            }
            *reinterpret_cast<float4*>(out + S + a + 4u * v) =
                make_float4(vals[0], vals[1], vals[2], vals[3]);
        }
    }
}

extern "C" void kernel_launch(void* const* d_in, const int* in_sizes, int n_in,
                              void* d_out, int out_size, void* d_ws, size_t ws_size,
                              hipStream_t stream)
{
    const float* x = (const float*)d_in[0];
    float* out = (float*)d_out;
    unfold223_v3<<<dim3(NBANDS, 256), dim3(256), 0, stream>>>(x, out);
}

// Round 4
// 517.484 us; speedup vs baseline: 1.0806x; 1.0806x over previous
//
#include <hip/hip_runtime.h>

// Unfold (im2col): IN (4,64,224,224) f32, K=3x3, pad=1, stride=1, dil=1
// (reference nh=k+dil quirk -> output spatial 223x223)
// out[ch][pos], ch=(b*64+c)*9+i*3+j (2304 channels), pos=oh*223+ow (49729)
//   = x[b,c,oh+i-1,ow+j-1] (zero-padded)
//
// V4: padding only touches output row 0 (i=0) and col 0 (j=0), so ~97% of
// 16B output quads are pure skewed copies: ONE unaligned dwordx4 load +
// ONE aligned NT dwordx4 store (VMEM mix 17 -> 2 insts per 16B vs V2).
// Slow path (row-cross / pad-adjacent quads) is exec-masked scalar gather;
// the store stays uniform. NT stores keep the 9x-reused input in L2.

#define OW       223u
#define OSP      49729u      // 223*223
#define IW       224u
#define PLANE_IN 50176u      // 224*224
#define NCH      2304u       // 4*64*9

typedef float vf4 __attribute__((ext_vector_type(4)));
typedef vf4 vf4u __attribute__((aligned(4)));   // 4B-aligned vector view

__global__ __launch_bounds__(256) void unfold223_v4(
    const float* __restrict__ x, float* __restrict__ out)
{
    const unsigned ch = blockIdx.y;            // (b*64+c)*9 + i*3 + j (uniform)
    const unsigned q  = ch / 9u;               // SALU
    const unsigned r  = ch - q * 9u;
    const int im1 = (int)(r / 3u) - 1;         // i-1 (uniform)
    const int jm1 = (int)(r % 3u) - 1;         // j-1 (uniform)
    const int off = im1 * (int)IW + jm1;       // uniform src offset
    const float* __restrict__ xq = x + q * PLANE_IN;
    float* __restrict__ och = out + (unsigned long long)ch * OSP;

    // OSP % 4 == 1 -> channel base alignment rotates; a = first 16B-aligned elem
    const unsigned a  = (4u - (ch & 3u)) & 3u;
    const unsigned nv = (OSP - a) >> 2;        // aligned quad count
    const unsigned tid = threadIdx.x;

    // head [0,a) + tail: <=5 scalar elems per channel (block x==0 only)
    if (blockIdx.x == 0u && tid < 8u) {
        const unsigned nhead = a;
        const unsigned ntail = OSP - a - 4u * nv;
        if (tid < nhead + ntail) {
            unsigned pos = (tid < nhead) ? tid : (a + 4u * nv + (tid - nhead));
            unsigned oh = pos / OW;
            unsigned ow = pos - oh * OW;
            int ih = (int)oh + im1;
            int iw = (int)ow + jm1;
            bool valid = ((unsigned)ih < 224u) && ((unsigned)iw < 224u);
            unsigned idx = valid ? ((unsigned)ih * IW + (unsigned)iw) : 0u;
            float val = xq[idx];
            och[pos] = valid ? val : 0.0f;
        }
    }

    // main: 4 quads per thread, block-strided
    const unsigned vbase = blockIdx.x * 1024u + tid;
#pragma unroll
    for (int k = 0; k < 4; ++k) {
        const unsigned v = vbase + (unsigned)(k * 256);
        if (v < nv) {
            const unsigned pos = a + 4u * v;
            const unsigned oh0 = pos / OW;         // one magic-mul divide
            const unsigned ow0 = pos - oh0 * OW;
            // src flat index of elem0: (oh0+im1)*224 + ow0+jm1 = pos + oh0 + off
            const int src = (int)pos + (int)oh0 + (int)off;
            // fast iff no row-cross and no pad touch:
            //   ow0<=219 (quad stays in row; also iw0+3<=223)
            //   ow0+jm1>=0 (left pad only when j=0,ow0=0)
            //   oh0+im1>=0 (top pad only when i=0,oh0=0)
            const bool fast = (ow0 <= 219u)
                           && ((int)ow0 + jm1 >= 0)
                           && ((int)oh0 + im1 >= 0);
            vf4 res;
            if (fast) {
                res = *reinterpret_cast<const vf4u*>(xq + src);
            } else {
                float vals[4];
#pragma unroll
                for (int e = 0; e < 4; ++e) {
                    unsigned ow = ow0 + (unsigned)e;
                    unsigned oh = oh0;
                    if (ow >= OW) { ow -= OW; oh += 1u; }
                    int ih = (int)oh + im1;
                    int iw = (int)ow + jm1;
                    bool valid = ((unsigned)ih < 224u) && ((unsigned)iw < 224u);
                    unsigned idx = valid ? ((unsigned)ih * IW + (unsigned)iw) : 0u;
                    float val = xq[idx];
                    vals[e] = valid ? val : 0.0f;
                }
                res[0] = vals[0]; res[1] = vals[1];
                res[2] = vals[2]; res[3] = vals[3];
            }
            __builtin_nontemporal_store(res, reinterpret_cast<vf4*>(och + pos));
        }
    }
}

extern "C" void kernel_launch(void* const* d_in, const int* in_sizes, int n_in,
                              void* d_out, int out_size, void* d_ws, size_t ws_size,
                              hipStream_t stream)
{
    const float* x = (const float*)d_in[0];
    float* out = (float*)d_out;
    // max nv = 12432 -> ceil(12432/1024) = 13 blocks in x
    unfold223_v4<<<dim3(13, NCH), dim3(256), 0, stream>>>(x, out);
}